// Round 2
// baseline (183.274 us; speedup 1.0000x reference)
//
#include <hip/hip_runtime.h>

#define NEG_BIG (-3.0e38f)

__device__ inline float rdlane(float x, int l) {
  return __int_as_float(__builtin_amdgcn_readlane(__float_as_int(x), l));
}

// One wave64 per sample. Lane m owns lags sh = 4m..4m+3 (sh=255 is a dummy).
// apad (wave-private LDS): zeros[0,128) | raw audio [128,256) | zeros [256,384).
// corr_raw[sh] = sum_j v[j] * apad[255 + j - sh]; normalization folded in at the end.
__global__ __launch_bounds__(256) void avsync_kernel(
    const float* __restrict__ video, const float* __restrict__ audio,
    const float* __restrict__ W1, const float* __restrict__ b1,
    const float* __restrict__ W2, const float* __restrict__ b2,
    float* __restrict__ out) {
  __shared__ float lds[4][384];

  const int tid = threadIdx.x;
  const int wid = tid >> 6;
  const int m   = tid & 63;
  const int b   = (int)blockIdx.x * 4 + wid;
  float* ap = lds[wid];

  const float2 vv = *reinterpret_cast<const float2*>(video + (size_t)b * 128 + 2 * m);
  const float2 aa = *reinterpret_cast<const float2*>(audio + (size_t)b * 128 + 2 * m);

  // stage RAW audio immediately (no dependency on the norm reduction)
  float2 z2; z2.x = 0.f; z2.y = 0.f;
  reinterpret_cast<float2*>(ap)[m]       = z2;   // floats [0,128)
  reinterpret_cast<float2*>(ap)[64 + m]  = aa;   // floats [128,256)
  reinterpret_cast<float2*>(ap)[128 + m] = z2;   // floats [256,384)

  // norms over the full wave
  float pv = vv.x * vv.x + vv.y * vv.y;
  float pa = aa.x * aa.x + aa.y * aa.y;
#pragma unroll
  for (int off = 1; off < 64; off <<= 1) {
    pv += __shfl_xor(pv, off, 64);
    pa += __shfl_xor(pa, off, 64);
  }
  const float nv = sqrtf(pv);
  const float na = sqrtf(pa);
  const float iv = 1.0f / fmaxf(nv, 1e-12f);
  const float ia = 1.0f / fmaxf(na, 1e-12f);

  // phase statistic on normalized difference
  const float d0 = vv.x * iv - aa.x * ia;
  const float d1 = vv.y * iv - aa.y * ia;
  float sc = __cosf(d0) + __cosf(d1);
  float ss = __sinf(d0) + __sinf(d1);
#pragma unroll
  for (int off = 1; off < 64; off <<= 1) {
    sc += __shfl_xor(sc, off, 64);
    ss += __shfl_xor(ss, off, 64);
  }

  // sliding-window correlation on RAW data.
  // window W[t] = apad[(252 + 4c - 4m) + t], t=0..7 ; acc[q] += v[4c+e] * W[3+e-q]
  const int baseByte = (63 - m) * 16;          // byte offset of slot (63-m)
  const char* apc = reinterpret_cast<const char*>(ap);
  float W[8];
  {
    const float4 t0 = *reinterpret_cast<const float4*>(apc + baseByte);
    const float4 t1 = *reinterpret_cast<const float4*>(apc + baseByte + 16);
    W[0] = t0.x; W[1] = t0.y; W[2] = t0.z; W[3] = t0.w;
    W[4] = t1.x; W[5] = t1.y; W[6] = t1.z; W[7] = t1.w;
  }
  float acc[4] = {0.f, 0.f, 0.f, 0.f};
#pragma unroll
  for (int c = 0; c < 32; ++c) {
    const float v0 = rdlane(vv.x, 2 * c);
    const float v1 = rdlane(vv.y, 2 * c);
    const float v2 = rdlane(vv.x, 2 * c + 1);
    const float v3 = rdlane(vv.y, 2 * c + 1);

    acc[0] = fmaf(v0, W[3], acc[0]);
    acc[1] = fmaf(v0, W[2], acc[1]);
    acc[2] = fmaf(v0, W[1], acc[2]);
    acc[3] = fmaf(v0, W[0], acc[3]);

    acc[0] = fmaf(v1, W[4], acc[0]);
    acc[1] = fmaf(v1, W[3], acc[1]);
    acc[2] = fmaf(v1, W[2], acc[2]);
    acc[3] = fmaf(v1, W[1], acc[3]);

    acc[0] = fmaf(v2, W[5], acc[0]);
    acc[1] = fmaf(v2, W[4], acc[1]);
    acc[2] = fmaf(v2, W[3], acc[2]);
    acc[3] = fmaf(v2, W[2], acc[3]);

    acc[0] = fmaf(v3, W[6], acc[0]);
    acc[1] = fmaf(v3, W[5], acc[1]);
    acc[2] = fmaf(v3, W[4], acc[2]);
    acc[3] = fmaf(v3, W[3], acc[3]);

    if (c < 31) {
      const float4 tn = *reinterpret_cast<const float4*>(apc + baseByte + 32 + 16 * c);
      W[0] = W[4]; W[1] = W[5]; W[2] = W[6]; W[3] = W[7];
      W[4] = tn.x; W[5] = tn.y; W[6] = tn.z; W[7] = tn.w;
    }
  }

  // per-lane stats over 4 lags (ascending -> first-occurrence argmax)
  float sum = 0.f, ssq = 0.f, mx = NEG_BIG;
  int mi = 0;
#pragma unroll
  for (int q = 0; q < 4; ++q) {
    const int sh = 4 * m + q;
    const bool realLag = (sh < 255);
    const float cv = acc[q];
    const float cs = realLag ? cv : 0.f;
    sum += cs;
    ssq += cs * cs;
    const float cm = realLag ? cv : NEG_BIG;
    if (cm > mx) { mx = cm; mi = sh; }
  }
#pragma unroll
  for (int off = 1; off < 64; off <<= 1) {
    const float ov = __shfl_xor(mx, off, 64);
    const int   oi = __shfl_xor(mi, off, 64);
    if (ov > mx || (ov == mx && oi < mi)) { mx = ov; mi = oi; }
    sum += __shfl_xor(sum, off, 64);
    ssq += __shfl_xor(ssq, off, 64);
  }

  // fold normalization: corr_normalized = (iv*ia) * corr_raw
  const float s = iv * ia;
  const float delay = (float)mi - 127.0f;
  const float rv = nv / fmaxf(nv, 1e-12f);   // ||v_normalized|| (=1)
  const float ra = na / fmaxf(na, 1e-12f);
  const float cstr = (mx * s) / (rv * ra + 1e-6f);
  const float mean_r = sum * (1.0f / 255.0f);
  const float var_r  = fmaxf(ssq * (1.0f / 255.0f) - mean_r * mean_r, 0.0f);
  const float cstd = s * sqrtf(var_r);
  const float ve = rv * rv, ae = ra * ra;
  const float er = ve / (ae + 1e-6f);
  const float mc = sc * (1.0f / 128.0f), ms = ss * (1.0f / 128.0f);
  const float pc = sqrtf(mc * mc + ms * ms);
  const float cons = 1.0f / (1.0f + fabsf(delay));

  const float s0 = delay * 0.1f;
  const float s1 = cstr;
  const float s2 = cstd;
  const float s3 = er;
  const float s4 = pc;
  const float s5 = cons;

  // MLP: lane f (< 32) computes output feature f
  const int f = m & 31;
  float h[16];
#pragma unroll
  for (int k = 0; k < 16; ++k) {
    float acch = b1[k];
    acch = fmaf(s0, W1[0 * 16 + k], acch);
    acch = fmaf(s1, W1[1 * 16 + k], acch);
    acch = fmaf(s2, W1[2 * 16 + k], acch);
    acch = fmaf(s3, W1[3 * 16 + k], acch);
    acch = fmaf(s4, W1[4 * 16 + k], acch);
    acch = fmaf(s5, W1[5 * 16 + k], acch);
    h[k] = fmaxf(acch, 0.0f);
  }
  float o = b2[f];
#pragma unroll
  for (int k = 0; k < 16; ++k) o = fmaf(h[k], W2[k * 32 + f], o);
  if (m < 32) out[(size_t)b * 32 + f] = o;
}

extern "C" void kernel_launch(void* const* d_in, const int* in_sizes, int n_in,
                              void* d_out, int out_size, void* d_ws, size_t ws_size,
                              hipStream_t stream) {
  const float* video = (const float*)d_in[0];
  const float* audio = (const float*)d_in[1];
  const float* W1 = (const float*)d_in[2];
  const float* b1 = (const float*)d_in[3];
  const float* W2 = (const float*)d_in[4];
  const float* b2 = (const float*)d_in[5];
  float* out = (float*)d_out;

  const int B = in_sizes[0] / 128;        // 65536 samples
  const int blocks = B / 4;               // 1 sample/wave * 4 waves/block
  avsync_kernel<<<blocks, 256, 0, stream>>>(video, audio, W1, b1, W2, b2, out);
}

// Round 3
// 88.672 us; speedup vs baseline: 2.0669x; 2.0669x over previous
//
#include <hip/hip_runtime.h>

#define NEG_BIG (-3.0e38f)

// 16B-slot XOR swizzle: spreads stride-2-slot lane patterns across all 8
// bank-groups of each 128B LDS row (structural-minimum phases per b128).
__device__ __forceinline__ int swz(int s) { return s ^ ((s >> 3) & 7); }

// One block = 256 threads = 4 waves; each wave handles 2 samples (32 lanes each).
// Lane m (within its half) owns lags sh = (248-8m) .. (248-8m)+7  (sh=255 dummy).
// apad floats [0,384): zeros | raw audio at [128,256) | zeros, stored XOR-swizzled
// at 16B-slot granularity. vl: raw video, linear (broadcast reads only).
// corr_raw[sh] = sum_j v[j]*apad[255+j-sh]; window W[t] = apad[8m+4c+t], t=0..11;
// acc[q] += v[4c+e] * W[7+e-q]. Normalization folded in at the end.
__global__ __launch_bounds__(256) void avsync_kernel(
    const float* __restrict__ video, const float* __restrict__ audio,
    const float* __restrict__ W1, const float* __restrict__ b1,
    const float* __restrict__ W2, const float* __restrict__ b2,
    float* __restrict__ out) {
  __shared__ float lds[4][2][512];   // per half: 96 slots apad + 128 floats vl

  const int tid  = threadIdx.x;
  const int wid  = tid >> 6;
  const int lane = tid & 63;
  const int half = lane >> 5;
  const int m    = lane & 31;
  const int b    = (int)blockIdx.x * 8 + wid * 2 + half;

  float* ap  = &lds[wid][half][0];
  float* vl  = &lds[wid][half][384];
  char*  apc = reinterpret_cast<char*>(ap);

  const float4 vr = *reinterpret_cast<const float4*>(video + (size_t)b * 128 + 4 * m);
  const float4 ar = *reinterpret_cast<const float4*>(audio + (size_t)b * 128 + 4 * m);

  // stage RAW data immediately (no dependency on reductions)
  float4 z4; z4.x = z4.y = z4.z = z4.w = 0.0f;
  *reinterpret_cast<float4*>(apc + (swz(m)      << 4)) = z4;  // floats [0,128)
  *reinterpret_cast<float4*>(apc + (swz(32 + m) << 4)) = ar;  // floats [128,256)
  *reinterpret_cast<float4*>(apc + (swz(64 + m) << 4)) = z4;  // floats [256,384)
  reinterpret_cast<float4*>(vl)[m] = vr;

  // norms (width-32: per half)
  float pv = vr.x * vr.x + vr.y * vr.y + vr.z * vr.z + vr.w * vr.w;
  float pa = ar.x * ar.x + ar.y * ar.y + ar.z * ar.z + ar.w * ar.w;
#pragma unroll
  for (int off = 1; off < 32; off <<= 1) {
    pv += __shfl_xor(pv, off, 32);
    pa += __shfl_xor(pa, off, 32);
  }
  const float nv = sqrtf(pv);
  const float na = sqrtf(pa);
  const float iv = 1.0f / fmaxf(nv, 1e-12f);
  const float ia = 1.0f / fmaxf(na, 1e-12f);

  // phase statistic on normalized difference
  const float d0 = vr.x * iv - ar.x * ia;
  const float d1 = vr.y * iv - ar.y * ia;
  const float d2 = vr.z * iv - ar.z * ia;
  const float d3 = vr.w * iv - ar.w * ia;
  float sc = __cosf(d0) + __cosf(d1) + __cosf(d2) + __cosf(d3);
  float ss = __sinf(d0) + __sinf(d1) + __sinf(d2) + __sinf(d3);
#pragma unroll
  for (int off = 1; off < 32; off <<= 1) {
    sc += __shfl_xor(sc, off, 32);
    ss += __shfl_xor(ss, off, 32);
  }

  // ---- main correlation loop ----
  float W[12];
  {
    const float4 t0 = *reinterpret_cast<const float4*>(apc + (swz(2 * m)     << 4));
    const float4 t1 = *reinterpret_cast<const float4*>(apc + (swz(2 * m + 1) << 4));
    const float4 t2 = *reinterpret_cast<const float4*>(apc + (swz(2 * m + 2) << 4));
    W[0] = t0.x; W[1] = t0.y; W[2]  = t0.z; W[3]  = t0.w;
    W[4] = t1.x; W[5] = t1.y; W[6]  = t1.z; W[7]  = t1.w;
    W[8] = t2.x; W[9] = t2.y; W[10] = t2.z; W[11] = t2.w;
  }
  const float4* vlp = reinterpret_cast<const float4*>(vl);
  float acc[8] = {0.f, 0.f, 0.f, 0.f, 0.f, 0.f, 0.f, 0.f};
#pragma unroll
  for (int c = 0; c < 32; ++c) {
    const float4 v4 = vlp[c];
#pragma unroll
    for (int q = 0; q < 8; ++q) {
      acc[q] = fmaf(v4.x, W[7 - q],  acc[q]);
      acc[q] = fmaf(v4.y, W[8 - q],  acc[q]);
      acc[q] = fmaf(v4.z, W[9 - q],  acc[q]);
      acc[q] = fmaf(v4.w, W[10 - q], acc[q]);
    }
    if (c < 31) {
      const float4 tn = *reinterpret_cast<const float4*>(apc + (swz(2 * m + 3 + c) << 4));
#pragma unroll
      for (int k = 0; k < 8; ++k) W[k] = W[k + 4];
      W[8] = tn.x; W[9] = tn.y; W[10] = tn.z; W[11] = tn.w;
    }
  }

  // per-lane stats over 8 lags, base sh0 = 248-8m (descending in m; ascending in q)
  const int sh0 = 248 - 8 * m;
  float sum = 0.f, ssq = 0.f, mx = NEG_BIG;
  int mi = 0;
#pragma unroll
  for (int q = 0; q < 8; ++q) {
    const int sh = sh0 + q;
    const bool realLag = (sh < 255);
    const float cv = acc[q];
    const float cs = realLag ? cv : 0.f;
    sum += cs;
    ssq += cs * cs;
    const float cm = realLag ? cv : NEG_BIG;
    if (cm > mx) { mx = cm; mi = sh; }
  }
#pragma unroll
  for (int off = 1; off < 32; off <<= 1) {
    const float ov = __shfl_xor(mx, off, 32);
    const int   oi = __shfl_xor(mi, off, 32);
    if (ov > mx || (ov == mx && oi < mi)) { mx = ov; mi = oi; }
    sum += __shfl_xor(sum, off, 32);
    ssq += __shfl_xor(ssq, off, 32);
  }

  // fold normalization: corr_normalized = (iv*ia) * corr_raw
  const float s = iv * ia;
  const float delay = (float)mi - 127.0f;
  const float rv = nv / fmaxf(nv, 1e-12f);   // ||v_normalized|| (=1)
  const float ra = na / fmaxf(na, 1e-12f);
  const float cstr = (mx * s) / (rv * ra + 1e-6f);
  const float mean_r = sum * (1.0f / 255.0f);
  const float var_r  = fmaxf(ssq * (1.0f / 255.0f) - mean_r * mean_r, 0.0f);
  const float cstd = s * sqrtf(var_r);
  const float ve = rv * rv, ae = ra * ra;
  const float er = ve / (ae + 1e-6f);
  const float mc = sc * (1.0f / 128.0f), ms = ss * (1.0f / 128.0f);
  const float pc = sqrtf(mc * mc + ms * ms);
  const float cons = 1.0f / (1.0f + fabsf(delay));

  const float s0 = delay * 0.1f;
  const float s1 = cstr;
  const float s2 = cstd;
  const float s3 = er;
  const float s4 = pc;
  const float s5 = cons;

  // MLP: lane m of each half computes output feature m for its sample
  float h[16];
#pragma unroll
  for (int k = 0; k < 16; ++k) {
    float acch = b1[k];
    acch = fmaf(s0, W1[0 * 16 + k], acch);
    acch = fmaf(s1, W1[1 * 16 + k], acch);
    acch = fmaf(s2, W1[2 * 16 + k], acch);
    acch = fmaf(s3, W1[3 * 16 + k], acch);
    acch = fmaf(s4, W1[4 * 16 + k], acch);
    acch = fmaf(s5, W1[5 * 16 + k], acch);
    h[k] = fmaxf(acch, 0.0f);
  }
  float o = b2[m];
#pragma unroll
  for (int k = 0; k < 16; ++k) o = fmaf(h[k], W2[k * 32 + m], o);
  out[(size_t)b * 32 + m] = o;
}

extern "C" void kernel_launch(void* const* d_in, const int* in_sizes, int n_in,
                              void* d_out, int out_size, void* d_ws, size_t ws_size,
                              hipStream_t stream) {
  const float* video = (const float*)d_in[0];
  const float* audio = (const float*)d_in[1];
  const float* W1 = (const float*)d_in[2];
  const float* b1 = (const float*)d_in[3];
  const float* W2 = (const float*)d_in[4];
  const float* b2 = (const float*)d_in[5];
  float* out = (float*)d_out;

  const int B = in_sizes[0] / 128;        // 65536 samples
  const int blocks = B / 8;               // 2 samples/wave * 4 waves/block
  avsync_kernel<<<blocks, 256, 0, stream>>>(video, audio, W1, b1, W2, b2, out);
}